// Round 4
// baseline (252.581 us; speedup 1.0000x reference)
//
#include <hip/hip_runtime.h>

#define NN   1024
#define TT   12
#define CC   64
#define DD   64
#define HH   2
#define KK   3
#define ETOT 17408           // E (16384) + N self loops
#define BT   48              // B*T
#define BTH  96              // B*T*H
#define HD   128             // H*D
#define NBTG 6               // BT/8  (8 bt per block)
#define CSR_CAP (KK * ETOT + 8 * NN)   // padded combined CSR capacity

__device__ __forceinline__ float bf_lo(unsigned int u) {
    return __uint_as_float(u << 16);
}
__device__ __forceinline__ float bf_hi(unsigned int u) {
    return __uint_as_float(u & 0xFFFF0000u);
}
__device__ __forceinline__ unsigned short f2bf(float f) {
    unsigned int u = __float_as_uint(f);
    u += 0x7FFFu + ((u >> 16) & 1u);      // round-to-nearest-even
    return (unsigned short)(u >> 16);
}
__device__ __forceinline__ unsigned int pack2(float a, float b) {
    return (unsigned int)f2bf(a) | ((unsigned int)f2bf(b) << 16);
}

// ---------------- Pass 0: alc/arc = fc_w @ attn_{l,r}  [K,H,C] --------------
__global__ __launch_bounds__(64) void prep_alc(
    const float* __restrict__ fc_w, const float* __restrict__ attn_l,
    const float* __restrict__ attn_r, float* __restrict__ alc, float* __restrict__ arc)
{
    int kh = blockIdx.x;            // 0..5
    int k = kh >> 1, h = kh & 1;
    int c = threadIdx.x;            // 0..63
    float sl = 0.f, sr = 0.f;
    #pragma unroll
    for (int d = 0; d < 64; ++d) {
        float w = fc_w[k * CC * HD + c * HD + h * 64 + d];
        sl = fmaf(w, attn_l[k * HD + h * 64 + d], sl);
        sr = fmaf(w, attn_r[k * HD + h * 64 + d], sr);
    }
    alc[kh * 64 + c] = sl;
    arc[kh * 64 + c] = sr;
}

// ---------------- Pass A: feat = x @ fc_w (bf16 packed), plus el/er ---------
// featp (uint4): [K*N, NBTG, 128]; lane e's uint4 packs feat[bt=btg*8+0..7][e]
// el/er: [K*N, h*BT+bt]
__global__ __launch_bounds__(128) void feat_kernel(
    const float* __restrict__ x,       // [B,N,T,C]
    const float* __restrict__ fc_w,    // [K,C,HD]
    const float* __restrict__ alc,     // [K,H,C]
    const float* __restrict__ arc,
    uint4* __restrict__ featp,
    float* __restrict__ el,
    float* __restrict__ er)
{
    int k = blockIdx.x / NN;
    int n = blockIdx.x % NN;
    int e = threadIdx.x;          // 0..127

    __shared__ float x_lds[BT * CC];   // 12 KB

    float wreg[CC];
    #pragma unroll
    for (int c = 0; c < CC; ++c) wreg[c] = fc_w[k * CC * HD + c * HD + e];

    for (int i = e; i < BT * CC; i += 128) {
        int bt = i >> 6, c = i & 63;
        int b = bt / TT, t = bt - b * TT;
        x_lds[i] = x[(((size_t)b * NN + n) * TT + t) * CC + c];
    }
    __syncthreads();

    // el/er via precomputed coefficient vectors (no shuffles)
    if (e < BTH) {
        int hh = e / BT, bt = e - hh * BT;
        const float* alp = &alc[(k * HH + hh) * CC];
        const float* arp = &arc[(k * HH + hh) * CC];
        const float* xr = &x_lds[bt * CC];
        float sl = 0.f, sr = 0.f;
        #pragma unroll
        for (int cc = 0; cc < CC; ++cc) {
            int c = (cc + bt) & 63;           // stagger: avoid 32-way LDS conflict
            float xv = xr[c];
            sl = fmaf(xv, alp[c], sl);
            sr = fmaf(xv, arp[c], sr);
        }
        el[(k * NN + n) * BTH + e] = sl;
        er[(k * NN + n) * BTH + e] = sr;
    }

    for (int btg = 0; btg < NBTG; ++btg) {
        float f8[8];
        #pragma unroll
        for (int i = 0; i < 8; ++i) {
            int bt = btg * 8 + i;
            const float* xr = &x_lds[bt * CC];
            float f = 0.f;
            #pragma unroll
            for (int c4 = 0; c4 < CC / 4; ++c4) {
                float4 xv = *(const float4*)&xr[c4 * 4];
                f = fmaf(xv.x, wreg[c4 * 4 + 0], f);
                f = fmaf(xv.y, wreg[c4 * 4 + 1], f);
                f = fmaf(xv.z, wreg[c4 * 4 + 2], f);
                f = fmaf(xv.w, wreg[c4 * 4 + 3], f);
            }
            f8[i] = f;
        }
        uint4 pk;
        pk.x = pack2(f8[0], f8[1]);
        pk.y = pack2(f8[2], f8[3]);
        pk.z = pack2(f8[4], f8[5]);
        pk.w = pack2(f8[6], f8[7]);
        featp[(size_t)((k * NN + n) * NBTG + btg) * 128 + e] = pk;
    }
}

// ---------------- CSR build (combined, k-segmented, rows padded to 8) -------
__global__ void count_kernel(const int* __restrict__ dst_idx, int* __restrict__ counts)
{
    int tid = blockIdx.x * blockDim.x + threadIdx.x;
    if (tid < KK * ETOT) {
        int k = tid / ETOT;
        atomicAdd(&counts[k * NN + dst_idx[tid]], 1);
    }
}

__global__ __launch_bounds__(1024) void scan_kernel(
    const int* __restrict__ counts,
    int* __restrict__ comb_start,    // [NN+1], multiples of 8
    int* __restrict__ seg_starts,    // [K*NN]
    int* __restrict__ cursor,        // [K*NN]
    int* __restrict__ csr_comb)      // pad entries filled here
{
    int n = threadIdx.x;
    int c0 = counts[n], c1 = counts[NN + n], c2 = counts[2 * NN + n];
    int tot = c0 + c1 + c2;
    int padded = (tot + 7) & ~7;
    __shared__ int buf[NN];
    buf[n] = padded;
    __syncthreads();
    for (int off = 1; off < NN; off <<= 1) {
        int v = (n >= off) ? buf[n - off] : 0;
        __syncthreads();
        buf[n] += v;
        __syncthreads();
    }
    int incl = buf[n];
    int excl = incl - padded;
    comb_start[n] = excl;
    if (n == NN - 1) comb_start[NN] = incl;
    seg_starts[n] = excl;
    seg_starts[NN + n] = excl + c0;
    seg_starts[2 * NN + n] = excl + c0 + c1;
    cursor[n] = excl;
    cursor[NN + n] = excl + c0;
    cursor[2 * NN + n] = excl + c0 + c1;
    for (int j = excl + tot; j < excl + padded; ++j) csr_comb[j] = n;  // pad: k=0,src=n (alpha=0)
}

__global__ void scatter_kernel(const int* __restrict__ src_idx,
                               const int* __restrict__ dst_idx,
                               int* __restrict__ cursor, int* __restrict__ csr_comb)
{
    int tid = blockIdx.x * blockDim.x + threadIdx.x;
    if (tid < KK * ETOT) {
        int k = tid / ETOT;
        int pos = atomicAdd(&cursor[k * NN + dst_idx[tid]], 1);
        csr_comb[pos] = k * NN + src_idx[tid];
    }
}

// ---------------- Pass C: softmax, prescaled alpha --------------------------
// alpha[j*BTH + bth] = exp(lrelu(el+er)) * weight[k] / denom   (combined-CSR order)
__global__ __launch_bounds__(96) void attn_kernel(
    const float* __restrict__ el, const float* __restrict__ er,
    const int* __restrict__ seg_starts, const int* __restrict__ counts,
    const int* __restrict__ csr_comb, const float* __restrict__ weight,
    float* __restrict__ alpha)
{
    int k = blockIdx.x / NN, n = blockIdx.x % NN;
    int bth = threadIdx.x;          // 0..95
    int base = seg_starts[k * NN + n];
    int len  = counts[k * NN + n];
    const int* csp = csr_comb + base;
    float erv = er[(k * NN + n) * BTH + bth];

    float s = 0.f;
    int j = 0;
    for (; j + 4 <= len; j += 4) {
        int sa = csp[j], sb = csp[j + 1], sc = csp[j + 2], sd = csp[j + 3];
        float ea = el[(size_t)sa * BTH + bth] + erv;
        float eb = el[(size_t)sb * BTH + bth] + erv;
        float ec = el[(size_t)sc * BTH + bth] + erv;
        float ed = el[(size_t)sd * BTH + bth] + erv;
        ea = ea > 0.f ? ea : ea * 0.2f;  eb = eb > 0.f ? eb : eb * 0.2f;
        ec = ec > 0.f ? ec : ec * 0.2f;  ed = ed > 0.f ? ed : ed * 0.2f;
        float aa = __expf(ea), ab = __expf(eb), ac = __expf(ec), ad = __expf(ed);
        alpha[(size_t)(base + j + 0) * BTH + bth] = aa;
        alpha[(size_t)(base + j + 1) * BTH + bth] = ab;
        alpha[(size_t)(base + j + 2) * BTH + bth] = ac;
        alpha[(size_t)(base + j + 3) * BTH + bth] = ad;
        s += (aa + ab) + (ac + ad);
    }
    for (; j < len; ++j) {
        int src = csp[j];
        float ev = el[(size_t)src * BTH + bth] + erv;
        ev = ev > 0.f ? ev : ev * 0.2f;
        float a = __expf(ev);
        alpha[(size_t)(base + j) * BTH + bth] = a;
        s += a;
    }
    float scale = weight[k] / s;
    j = 0;
    for (; j + 4 <= len; j += 4) {
        float a0 = alpha[(size_t)(base + j + 0) * BTH + bth];
        float a1 = alpha[(size_t)(base + j + 1) * BTH + bth];
        float a2 = alpha[(size_t)(base + j + 2) * BTH + bth];
        float a3 = alpha[(size_t)(base + j + 3) * BTH + bth];
        alpha[(size_t)(base + j + 0) * BTH + bth] = a0 * scale;
        alpha[(size_t)(base + j + 1) * BTH + bth] = a1 * scale;
        alpha[(size_t)(base + j + 2) * BTH + bth] = a2 * scale;
        alpha[(size_t)(base + j + 3) * BTH + bth] = a3 * scale;
    }
    for (; j < len; ++j)
        alpha[(size_t)(base + j) * BTH + bth] *= scale;
}

// ---------------- Pass D: aggregate (8 bt/block, 8 gathers in flight) -------
__global__ __launch_bounds__(128) void agg_merge_kernel(
    const uint4* __restrict__ featp,
    const float* __restrict__ alpha,
    const int* __restrict__ comb_start, const int* __restrict__ csr_comb,
    const float* __restrict__ gat_bias, const float* __restrict__ weight,
    const float* __restrict__ merge_w, const float* __restrict__ merge_b,
    const float* __restrict__ x, float* __restrict__ out)
{
    int btg = blockIdx.x >> 10;      // btg-major
    int n   = blockIdx.x & 1023;
    int e = threadIdx.x;             // 0..127
    int h = e >> 6;

    int rbeg = comb_start[n];
    int rend = comb_start[n + 1];    // both multiples of 8

    const float* alp = alpha + h * BT + btg * 8;
    const uint4* fb = featp + btg * 128 + e;

    float r[8];
    #pragma unroll
    for (int i = 0; i < 8; ++i) r[i] = 0.f;

    for (int j0 = rbeg; j0 < rend; j0 += 8) {
        int4 ia = *(const int4*)&csr_comb[j0];
        int4 ib = *(const int4*)&csr_comb[j0 + 4];
        int idx[8] = {ia.x, ia.y, ia.z, ia.w, ib.x, ib.y, ib.z, ib.w};
        uint4 f[8];
        #pragma unroll
        for (int u = 0; u < 8; ++u) f[u] = fb[(size_t)idx[u] * (NBTG * 128)];
        #pragma unroll
        for (int u = 0; u < 8; ++u) {
            const float* ap = &alp[(size_t)(j0 + u) * BTH];
            float4 A = *(const float4*)ap;
            float4 Bv = *(const float4*)(ap + 4);
            r[0] = fmaf(A.x,  bf_lo(f[u].x), r[0]);
            r[1] = fmaf(A.y,  bf_hi(f[u].x), r[1]);
            r[2] = fmaf(A.z,  bf_lo(f[u].y), r[2]);
            r[3] = fmaf(A.w,  bf_hi(f[u].y), r[3]);
            r[4] = fmaf(Bv.x, bf_lo(f[u].z), r[4]);
            r[5] = fmaf(Bv.y, bf_hi(f[u].z), r[5]);
            r[6] = fmaf(Bv.z, bf_lo(f[u].w), r[6]);
            r[7] = fmaf(Bv.w, bf_hi(f[u].w), r[7]);
        }
    }

    // + sum_k weight[k]*gat_bias[k][e]
    float wb = weight[0] * gat_bias[e] + weight[1] * gat_bias[HD + e]
             + weight[2] * gat_bias[2 * HD + e];
    #pragma unroll
    for (int i = 0; i < 8; ++i) r[i] += wb;

    __shared__ float rows[8][HD];    // 4 KB
    #pragma unroll
    for (int i = 0; i < 8; ++i) rows[i][e] = r[i];
    __syncthreads();

    #pragma unroll
    for (int pass = 0; pass < 4; ++pass) {
        int oi = pass * 128 + e;     // 512 outputs: 8 rows x 64 cols
        int rr = oi >> 6, dd = oi & 63;
        float mg = merge_b[dd];
        #pragma unroll
        for (int q = 0; q < HD; ++q) mg = fmaf(rows[rr][q], merge_w[q * DD + dd], mg);
        mg = mg > 0.f ? mg : mg * 0.01f;
        int bt = btg * 8 + rr;
        int b = bt / TT, t = bt - b * TT;
        size_t oidx = (((size_t)b * NN + n) * TT + t) * DD + dd;
        out[oidx] = mg + x[oidx];
    }
}

extern "C" void kernel_launch(void* const* d_in, const int* in_sizes, int n_in,
                              void* d_out, int out_size, void* d_ws, size_t ws_size,
                              hipStream_t stream)
{
    const float* x        = (const float*)d_in[0];
    const float* fc_w     = (const float*)d_in[1];
    const float* attn_l   = (const float*)d_in[2];
    const float* attn_r   = (const float*)d_in[3];
    const float* gat_bias = (const float*)d_in[4];
    const float* weight   = (const float*)d_in[5];
    const float* merge_w  = (const float*)d_in[6];
    const float* merge_b  = (const float*)d_in[7];
    const int*   src_idx  = (const int*)d_in[8];
    const int*   dst_idx  = (const int*)d_in[9];
    float*       out      = (float*)d_out;

    char* p = (char*)d_ws;
    auto carve = [&](size_t bytes) { char* r = p; p += (bytes + 15) & ~size_t(15); return r; };
    uint4* featp     = (uint4*)carve(sizeof(unsigned short) * (size_t)KK * NN * BT * HD); // 37.7 MB
    float* el        = (float*)carve(sizeof(float) * KK * NN * BTH);
    float* er        = (float*)carve(sizeof(float) * KK * NN * BTH);
    float* alpha     = (float*)carve(sizeof(float) * (size_t)CSR_CAP * BTH);              // ~23 MB
    float* alc       = (float*)carve(sizeof(float) * KK * HH * CC);
    float* arc       = (float*)carve(sizeof(float) * KK * HH * CC);
    int*   counts    = (int*)carve(sizeof(int) * KK * NN);
    int*   cursor    = (int*)carve(sizeof(int) * KK * NN);
    int*   seg_starts= (int*)carve(sizeof(int) * KK * NN);
    int*   comb_start= (int*)carve(sizeof(int) * (NN + 1));
    int*   csr_comb  = (int*)carve(sizeof(int) * (CSR_CAP + 16));

    hipMemsetAsync(counts, 0, sizeof(int) * KK * NN, stream);
    hipMemsetAsync(alpha, 0, sizeof(float) * (size_t)CSR_CAP * BTH, stream);

    prep_alc<<<KK * HH, 64, 0, stream>>>(fc_w, attn_l, attn_r, alc, arc);

    feat_kernel<<<KK * NN, 128, 0, stream>>>(x, fc_w, alc, arc, featp, el, er);

    int edgeBlocks = (KK * ETOT + 255) / 256;
    count_kernel<<<edgeBlocks, 256, 0, stream>>>(dst_idx, counts);
    scan_kernel<<<1, 1024, 0, stream>>>(counts, comb_start, seg_starts, cursor, csr_comb);
    scatter_kernel<<<edgeBlocks, 256, 0, stream>>>(src_idx, dst_idx, cursor, csr_comb);

    attn_kernel<<<KK * NN, 96, 0, stream>>>(el, er, seg_starts, counts, csr_comb, weight, alpha);

    agg_merge_kernel<<<NN * NBTG, 128, 0, stream>>>(
        featp, alpha, comb_start, csr_comb,
        gat_bias, weight, merge_w, merge_b, x, out);
}